// Round 6
// baseline (146.486 us; speedup 1.0000x reference)
//
#include <hip/hip_runtime.h>

// B=16, Q=256, K=256, H=256, DV=256
#define Bn 16
#define Qn 256
#define Kn 256
#define Hn 256
#define DVn 256

constexpr float C2    = 2.8853900817779268f;   // 2/ln2 : e^{2x} = 2^(C2*x)
constexpr float LOG2E = 1.4426950408889634f;

typedef __attribute__((ext_vector_type(8))) short bf16x8;
typedef __attribute__((ext_vector_type(4))) float f32x4;

__device__ __forceinline__ float fast_exp2(float x) { return __builtin_amdgcn_exp2f(x); }
__device__ __forceinline__ float fast_rcp(float x)  { return __builtin_amdgcn_rcpf(x); }

__device__ __forceinline__ unsigned short f2bf(float x) {   // RNE fp32->bf16
    unsigned u = __float_as_uint(x);
    u += 0x7fffu + ((u >> 16) & 1u);
    return (unsigned short)(u >> 16);
}

__device__ __forceinline__ bf16x8 cvt8(const float* p) {    // 8 fp32 -> bf16x8 fragment
    float4 x0 = *(const float4*)p;
    float4 x1 = *(const float4*)(p + 4);
    bf16x8 r;
    r[0] = (short)f2bf(x0.x); r[1] = (short)f2bf(x0.y);
    r[2] = (short)f2bf(x0.z); r[3] = (short)f2bf(x0.w);
    r[4] = (short)f2bf(x1.x); r[5] = (short)f2bf(x1.y);
    r[6] = (short)f2bf(x1.z); r[7] = (short)f2bf(x1.w);
    return r;
}

// ------------------------------------------------------------------
// K1 proj (MFMA), prep folded in:
//   rows 0..4095  = queries @ W_q^T -> Eq = exp(2*.) fp32 [4096][256]
//   rows 4096..8191 = keys  @ W_k^T -> Ek bf16 interleaved [b][h/4][k][4]
//   V re-tiled to k-quads fp32 [b][k/4][dv][4] (1 quad/thread).
// block = 256 thr (4 waves); block covers 16 m-rows x 128 n (grid 1024).
// ------------------------------------------------------------------
__global__ __launch_bounds__(256)
void proj_mfma_kernel(const float* __restrict__ q, const float* __restrict__ kx,
                      const float* __restrict__ wq, const float* __restrict__ wk,
                      const float* __restrict__ V,
                      float* __restrict__ Eq, unsigned short* __restrict__ Ekb,
                      float* __restrict__ Vp)
{
    const int tid  = threadIdx.x;
    const int wvid = tid >> 6, lane = tid & 63;
    const int bid  = blockIdx.x;                  // 0..1023
    const int m0   = (bid >> 1) * 16;             // 0..8191 (16-row blocks)
    const int n0   = (bid & 1) * 128 + wvid * 32; // this wave's 32-col slice
    const bool isQ = (m0 < 4096);
    const int r16  = lane & 15, q8 = (lane >> 4) * 8;

    // A fragments straight from fp32 global, converted in-register
    const float* Xrow = (isQ ? q + (size_t)(m0 + r16) * 256
                             : kx + (size_t)(m0 - 4096 + r16) * 256) + q8;
    bf16x8 afr[8];
    #pragma unroll
    for (int s = 0; s < 8; ++s) afr[s] = cvt8(Xrow + s * 32);

    const float* Wbase = isQ ? wq : wk;
    f32x4 acc[2];
    #pragma unroll
    for (int nt = 0; nt < 2; ++nt) {
        const float* Wrow = Wbase + (size_t)(n0 + nt * 16 + r16) * 256 + q8;
        f32x4 c = {0.f, 0.f, 0.f, 0.f};
        #pragma unroll
        for (int s = 0; s < 8; ++s) {
            bf16x8 bfr = cvt8(Wrow + s * 32);
            c = __builtin_amdgcn_mfma_f32_16x16x32_bf16(afr[s], bfr, c, 0, 0, 0);
        }
        acc[nt] = c;
    }
    const int rbase = (lane >> 4) * 4;
    #pragma unroll
    for (int nt = 0; nt < 2; ++nt) {
        const int n = n0 + nt * 16 + r16;
        #pragma unroll
        for (int r = 0; r < 4; ++r) {
            const int m = m0 + rbase + r;
            const float val = fast_exp2(C2 * acc[nt][r]);
            if (isQ) {
                Eq[(size_t)m * 256 + n] = val;
            } else {
                const int kr = m - 4096, b = kr >> 8, kk = kr & 255;
                Ekb[(((size_t)(b * 64 + (n >> 2))) * 256 + kk) * 4 + (n & 3)] = f2bf(val);
            }
        }
    }
    // V re-tile: one quad per thread, dv = tid (coalesced per row)
    {
        const int p   = bid * 256 + tid;          // 0..262143
        const int bk4 = p >> 8, dv = p & 255;
        const int b   = bk4 >> 6, k4 = bk4 & 63;
        const float* src = V + ((size_t)(b * Kn + 4 * k4)) * DVn + dv;
        float4 o;
        o.x = src[0 * DVn]; o.y = src[1 * DVn]; o.z = src[2 * DVn]; o.w = src[3 * DVn];
        *(float4*)(Vp + (size_t)p * 4) = o;
    }
}

// ------------------------------------------------------------------
// K2 fused: scores + softmax + PV -> out. 256 thr, 4 waves; thread owns
// k-column tid for 4 q-rows, full h range. R3 score math (1 rcp/h — the
// fastest measured form; R5's pairing bought nothing).
//
// THIS ROUND'S SINGLE VARIABLE: compact rolled loops. Five structurally
// different versions all sit at 51-55us with VALUBusy pinned at 58-63%
// regardless of occupancy (R1: 2x waves, dt=0), operand path (R0 s_load vs
// R3 LDS, dt=0), or op count (R5 -20% cycles, dt=0). A ~60% issue cap that
// waves can't lift and ops can't exploit = shared per-CU front end, i.e.
// I$ streaming from an unrolled ~40KB hot path (16x~200 + 64x~25 instr vs
// 32KB I$). Fix: #pragma unroll 1 + clamped prefetch indices (s_min, no
// branch, uniform body) on both score and PV loops.
// Prediction: VALUBusy>=80, dur ~34-40us. Falsifier: unchanged -> code size
// ruled out; next suspect = LDS broadcast return-bus (restructure to
// wave-per-q-row).
// score(q,k) = sum_h wv'_h / (1 + Eq[q,h]*Ek[k,h]),  wv' = -2*wv
// ------------------------------------------------------------------
__global__ __launch_bounds__(256)
void fused_attn_kernel(const float* __restrict__ Eq, const unsigned short* __restrict__ Ekb,
                       const float* __restrict__ wv, const float* __restrict__ Vp,
                       float* __restrict__ out)
{
    const int b   = blockIdx.y;
    const int q0  = blockIdx.x * 4;
    const int tid = threadIdx.x;

    __shared__ __align__(16) float sEq[4 * 256];   // 4KB: Eq tile [qq][h]
    __shared__ __align__(16) float sWv[256];       // 1KB: -2*wv
    __shared__ __align__(16) float sPv[256 * 4];   // 4KB: softmax probs [k][q]
    __shared__ float sredM[4][4];
    __shared__ float sredS[4][4];

    // ---- stage Eq tile + wv' into LDS (one coalesced pass) ----
    {
        const float* eqb = Eq + (size_t)(b * Qn + q0) * Hn;
        const int qq = tid >> 6, h4 = (tid & 63) * 4;
        *(float4*)&sEq[qq * 256 + h4] = *(const float4*)(eqb + qq * 256 + h4);
        if (tid < 64) {
            float4 wvec = *(const float4*)(wv + tid * 4);
            wvec.x *= -2.f; wvec.y *= -2.f; wvec.z *= -2.f; wvec.w *= -2.f;
            *(float4*)&sWv[tid * 4] = wvec;
        }
    }
    __syncthreads();

    float sc[4] = {0.f, 0.f, 0.f, 0.f};
    const uint2* ekp = (const uint2*)Ekb + (size_t)b * 16384 + tid;  // [b][h/4][k] quads
    uint2 e[4];
    #pragma unroll
    for (int g = 0; g < 4; ++g) e[g] = ekp[g * 256];
    #pragma unroll 1
    for (int it = 0; it < 16; ++it) {
        const int itn = (it < 15) ? (it + 1) : 15;   // uniform clamped prefetch (s_min)
        uint2 en[4];
        #pragma unroll
        for (int g = 0; g < 4; ++g) en[g] = ekp[(4 * itn + g) * 256];
        const int h0 = it * 16;
        #pragma unroll
        for (int g = 0; g < 4; ++g) {
            const float ek0 = __uint_as_float(e[g].x << 16);
            const float ek1 = __uint_as_float(e[g].x & 0xFFFF0000u);
            const float ek2 = __uint_as_float(e[g].y << 16);
            const float ek3 = __uint_as_float(e[g].y & 0xFFFF0000u);
            const float4 wa = *(const float4*)&sWv[h0 + 4 * g];                 // uniform ds
            #pragma unroll
            for (int qq = 0; qq < 4; ++qq) {
                const float4 ea = *(const float4*)&sEq[qq * 256 + h0 + 4 * g];  // uniform ds
                float a = sc[qq];
                a = fmaf(wa.x, fast_rcp(fmaf(ea.x, ek0, 1.f)), a);
                a = fmaf(wa.y, fast_rcp(fmaf(ea.y, ek1, 1.f)), a);
                a = fmaf(wa.z, fast_rcp(fmaf(ea.z, ek2, 1.f)), a);
                a = fmaf(wa.w, fast_rcp(fmaf(ea.w, ek3, 1.f)), a);
                sc[qq] = a;
            }
        }
        #pragma unroll
        for (int g = 0; g < 4; ++g) e[g] = en[g];
    }

    // ---- softmax over k (sc already carries -2 via wv') ----
    const int w = tid >> 6, lane = tid & 63;
    #pragma unroll
    for (int qq = 0; qq < 4; ++qq) {
        float mx = sc[qq];
        #pragma unroll
        for (int off = 32; off; off >>= 1) mx = fmaxf(mx, __shfl_xor(mx, off, 64));
        if (lane == 0) sredM[qq][w] = mx;
    }
    __syncthreads();
    float pq[4];
    #pragma unroll
    for (int qq = 0; qq < 4; ++qq) {
        const float mx = fmaxf(fmaxf(sredM[qq][0], sredM[qq][1]),
                               fmaxf(sredM[qq][2], sredM[qq][3]));
        pq[qq] = fast_exp2(LOG2E * (sc[qq] - mx));
        float s = pq[qq];
        #pragma unroll
        for (int off = 32; off; off >>= 1) s += __shfl_xor(s, off, 64);
        if (lane == 0) sredS[qq][w] = s;
    }
    *(float4*)&sPv[tid * 4] = make_float4(pq[0], pq[1], pq[2], pq[3]);
    __syncthreads();
    float rinv[4];
    #pragma unroll
    for (int qq = 0; qq < 4; ++qq)
        rinv[qq] = fast_rcp(sredS[qq][0] + sredS[qq][1] + sredS[qq][2] + sredS[qq][3]);

    // ---- PV: thread owns dv = tid, 4 q-rows; V in fp32 k-quad layout ----
    float acc[4] = {0.f, 0.f, 0.f, 0.f};
    const float4* vp = (const float4*)Vp + (size_t)b * 16384 + tid;
    float4 vv = vp[0];
    #pragma unroll 1
    for (int k4 = 0; k4 < 64; ++k4) {
        const int kn = (k4 < 63) ? (k4 + 1) : 63;    // uniform clamped prefetch
        float4 vn = vp[kn * 256];
        const float vj[4] = {vv.x, vv.y, vv.z, vv.w};
        #pragma unroll
        for (int j = 0; j < 4; ++j) {
            const float4 p4 = *(const float4*)&sPv[(4 * k4 + j) * 4];   // uniform broadcast
            acc[0] = fmaf(p4.x, vj[j], acc[0]);
            acc[1] = fmaf(p4.y, vj[j], acc[1]);
            acc[2] = fmaf(p4.z, vj[j], acc[2]);
            acc[3] = fmaf(p4.w, vj[j], acc[3]);
        }
        vv = vn;
    }
    float* ob = out + (size_t)(b * Qn + q0) * DVn + tid;
    ob[0 * DVn] = acc[0] * rinv[0];
    ob[1 * DVn] = acc[1] * rinv[1];
    ob[2 * DVn] = acc[2] * rinv[2];
    ob[3 * DVn] = acc[3] * rinv[3];
}

extern "C" void kernel_launch(void* const* d_in, const int* in_sizes, int n_in,
                              void* d_out, int out_size, void* d_ws, size_t ws_size,
                              hipStream_t stream) {
    const float* queries = (const float*)d_in[0];  // [16,256,256]
    const float* keys    = (const float*)d_in[1];  // [16,256,256]
    const float* values  = (const float*)d_in[2];  // [16,256,256]
    const float* W_q     = (const float*)d_in[3];  // [256,256]
    const float* W_k     = (const float*)d_in[4];  // [256,256]
    const float* w_v     = (const float*)d_in[5];  // [256]
    float* out = (float*)d_out;

    // workspace: Eq fp32 4MB | Ekb bf16 2MB | Vp fp32 4MB
    float*          Eq  = (float*)d_ws;
    unsigned short* Ekb = (unsigned short*)(Eq + (size_t)Bn * Qn * Hn);
    float*          Vp  = (float*)(Ekb + (size_t)Bn * Kn * Hn);

    proj_mfma_kernel<<<dim3(1024), 256, 0, stream>>>(queries, keys, W_q, W_k, values,
                                                     Eq, Ekb, Vp);
    fused_attn_kernel<<<dim3(64, 16), 256, 0, stream>>>(Eq, Ekb, w_v, Vp, out);
}

// Round 7
// 127.093 us; speedup vs baseline: 1.1526x; 1.1526x over previous
//
#include <hip/hip_runtime.h>
#include <hip/hip_fp16.h>

// B=16, Q=256, K=256, H=256, DV=256
#define Bn 16
#define Qn 256
#define Kn 256
#define Hn 256
#define DVn 256

constexpr float C2    = 2.8853900817779268f;   // 2/ln2 : e^{2x} = 2^(C2*x)
constexpr float LOG2E = 1.4426950408889634f;

typedef __attribute__((ext_vector_type(8))) short bf16x8;
typedef __attribute__((ext_vector_type(4))) float f32x4;

__device__ __forceinline__ float fast_exp2(float x) { return __builtin_amdgcn_exp2f(x); }
__device__ __forceinline__ float fast_rcp(float x)  { return __builtin_amdgcn_rcpf(x); }

__device__ __forceinline__ unsigned short f2bf(float x) {   // RNE fp32->bf16
    unsigned u = __float_as_uint(x);
    u += 0x7fffu + ((u >> 16) & 1u);
    return (unsigned short)(u >> 16);
}

// ------------------------------------------------------------------
// K0 prep (R0-measured): Xb = bf16(queries ++ keys)  [8192][256]
//          Wb = bf16(W_q ++ W_k)      [2][256][256]
//          Vp = V re-tiled to k-quads fp32 [b][k/4][dv][4]
// One wide-conversion pass; proj then reads bf16 directly (no per-fragment
// cvt). R1's fold of this into proj regressed the total by ~4us.
// grid 1024 x 256
// ------------------------------------------------------------------
__global__ __launch_bounds__(256)
void prep_kernel(const float* __restrict__ q, const float* __restrict__ kx,
                 const float* __restrict__ wq, const float* __restrict__ wk,
                 const float* __restrict__ V,
                 unsigned short* __restrict__ Xb, unsigned short* __restrict__ Wb,
                 float* __restrict__ Vp)
{
    const int g = blockIdx.x * 256 + threadIdx.x;   // 0..262143
    // X convert: 2M elements, 8 per thread
    {
        const float* xs = (g < 131072) ? (q + (size_t)g * 8)
                                       : (kx + (size_t)(g - 131072) * 8);
        float4 x0 = *(const float4*)xs;
        float4 x1 = *(const float4*)(xs + 4);
        ushort4 o0, o1;
        o0.x = f2bf(x0.x); o0.y = f2bf(x0.y); o0.z = f2bf(x0.z); o0.w = f2bf(x0.w);
        o1.x = f2bf(x1.x); o1.y = f2bf(x1.y); o1.z = f2bf(x1.z); o1.w = f2bf(x1.w);
        *(ushort4*)(Xb + (size_t)g * 8)     = o0;
        *(ushort4*)(Xb + (size_t)g * 8 + 4) = o1;
    }
    // W convert: 131072 elements, 4 per thread for g < 32768
    if (g < 32768) {
        const float* ws = (g < 16384) ? (wq + (size_t)g * 4)
                                      : (wk + (size_t)(g - 16384) * 4);
        float4 w0 = *(const float4*)ws;
        ushort4 o;
        o.x = f2bf(w0.x); o.y = f2bf(w0.y); o.z = f2bf(w0.z); o.w = f2bf(w0.w);
        *(ushort4*)(Wb + (size_t)g * 4) = o;
    }
    // V re-tile: quad p = g
    {
        const int p   = g;
        const int bk4 = p >> 8, dv = p & 255;
        const int b   = bk4 >> 6, k4 = bk4 & 63;
        const float* src = V + ((size_t)(b * Kn + 4 * k4)) * DVn + dv;
        float4 o;
        o.x = src[0 * DVn]; o.y = src[1 * DVn]; o.z = src[2 * DVn]; o.w = src[3 * DVn];
        *(float4*)(Vp + (size_t)p * 4) = o;
    }
}

// ------------------------------------------------------------------
// K1 proj (MFMA, R0-measured): reads pre-converted bf16 Xb/Wb.
//   rows 0..4095 = queries @ W_q^T -> Eq = exp(2*.) fp32 [4096][256]
//   rows 4096..8191 = keys @ W_k^T -> Ek bf16 interleaved [b][h/4][k][4]
// block = 256 thr (4 waves); block covers 16 m-rows x 256 n; wave 64 n.
// A/B fragments straight from global (no LDS, no cvt). grid 512.
// ------------------------------------------------------------------
__global__ __launch_bounds__(256)
void proj_mfma_kernel(const unsigned short* __restrict__ Xb,
                      const unsigned short* __restrict__ Wb,
                      float* __restrict__ Eq, unsigned short* __restrict__ Ekb)
{
    const int tid  = threadIdx.x;
    const int wvid = tid >> 6, lane = tid & 63;
    const int m0   = blockIdx.x * 16;          // 0..8191
    const int n0   = wvid * 64;
    const bool isQ = (m0 < 4096);
    const int r16  = lane & 15, q8 = (lane >> 4) * 8;

    const unsigned short* Xrow  = Xb + (size_t)(m0 + r16) * 256 + q8;
    const unsigned short* Wbase = Wb + (isQ ? 0 : 65536);

    bf16x8 afr[8];
    #pragma unroll
    for (int s = 0; s < 8; ++s) afr[s] = *(const bf16x8*)(Xrow + s * 32);

    f32x4 acc[4];
    #pragma unroll
    for (int nt = 0; nt < 4; ++nt) {
        const unsigned short* Wrow = Wbase + (size_t)(n0 + nt * 16 + r16) * 256 + q8;
        f32x4 c = {0.f, 0.f, 0.f, 0.f};
        #pragma unroll
        for (int s = 0; s < 8; ++s) {
            bf16x8 bfr = *(const bf16x8*)(Wrow + s * 32);
            c = __builtin_amdgcn_mfma_f32_16x16x32_bf16(afr[s], bfr, c, 0, 0, 0);
        }
        acc[nt] = c;
    }
    const int rbase = (lane >> 4) * 4;
    #pragma unroll
    for (int nt = 0; nt < 4; ++nt) {
        const int n = n0 + nt * 16 + r16;
        #pragma unroll
        for (int r = 0; r < 4; ++r) {
            const int m = m0 + rbase + r;
            const float val = fast_exp2(C2 * acc[nt][r]);
            if (isQ) {
                Eq[(size_t)m * 256 + n] = val;
            } else {
                const int kr = m - 4096, b = kr >> 8, kk = kr & 255;
                Ekb[(((size_t)(b * 64 + (n >> 2))) * 256 + kk) * 4 + (n & 3)] = f2bf(val);
            }
        }
    }
}

// ------------------------------------------------------------------
// K2 fused (R1-measured, best fused: 50.2us): scores + softmax + PV.
// 512 threads (8 waves), grid (Q/4=64, B=16).
// Half h = tid>>8 (wave-uniform via readfirstlane -> scalar Eq/wv loads):
//   score phase: thread owns k-column (tid&255), h-range [h*128, h*128+128)
//   PV phase:    thread owns dv = tid&255, k-range [h*128, h*128+128)
// score(q,k) = -2 * sum_h wv[h] * rcp(1 + Eq[q,h]*Ek[k,h])  (softmax shift-inv)
// Session finding: VALU-busy is invariant at ~31us across all 6 structural
// variants and utilization caps at ~63% -> this is the fused plateau.
// ------------------------------------------------------------------
__global__ __launch_bounds__(512, 8)
void fused_attn_kernel(const float* __restrict__ Eq, const unsigned short* __restrict__ Ekb,
                       const float* __restrict__ wv, const float* __restrict__ Vp,
                       float* __restrict__ out)
{
    const int b    = blockIdx.y;
    const int q0   = blockIdx.x * 4;
    const int tid  = threadIdx.x;
    const int kk   = tid & 255;
    const int half = tid >> 8;
    const int halfu = __builtin_amdgcn_readfirstlane(half);  // wave-uniform -> keeps Eq/wv loads scalar

    __shared__ __align__(16) float sPart[2][256][4];   // 8KB: score partials, then PV partials
    __shared__ __align__(16) float sPv[256 * 4];       // 4KB: softmax probs [k][q]
    __shared__ float sredM[4][8];
    __shared__ float sredS[4][8];

    const float* eq0 = Eq + (size_t)(b * Qn + q0) * Hn + halfu * 128;  // block+wave uniform
    const float* wv0 = wv + halfu * 128;

    float sc[4] = {0.f, 0.f, 0.f, 0.f};
    const uint2* ekp = (const uint2*)Ekb + (size_t)b * 16384 + (size_t)(halfu * 32) * 256 + kk;
    uint2 e[4];
    #pragma unroll
    for (int g = 0; g < 4; ++g) e[g] = ekp[g * 256];
    for (int it = 0; it < 8; ++it) {                  // 8 x 16 h = 128 h per half
        uint2 en[4];
        if (it < 7) {
            #pragma unroll
            for (int g = 0; g < 4; ++g) en[g] = ekp[(4 * (it + 1) + g) * 256];
        }
        const int h0 = it * 16;
        float ek[16];
        #pragma unroll
        for (int g = 0; g < 4; ++g) {
            ek[4*g+0] = __uint_as_float(e[g].x << 16);
            ek[4*g+1] = __uint_as_float(e[g].x & 0xFFFF0000u);
            ek[4*g+2] = __uint_as_float(e[g].y << 16);
            ek[4*g+3] = __uint_as_float(e[g].y & 0xFFFF0000u);
        }
        #pragma unroll
        for (int g = 0; g < 4; ++g) {
            const float4 wa = *(const float4*)(wv0 + h0 + 4 * g);              // s_load
            #pragma unroll
            for (int qq = 0; qq < 4; ++qq) {
                const float4 ea = *(const float4*)(eq0 + qq * 256 + h0 + 4 * g); // s_load
                float a = sc[qq];
                a = fmaf(wa.x, fast_rcp(fmaf(ea.x, ek[4*g+0], 1.f)), a);
                a = fmaf(wa.y, fast_rcp(fmaf(ea.y, ek[4*g+1], 1.f)), a);
                a = fmaf(wa.z, fast_rcp(fmaf(ea.z, ek[4*g+2], 1.f)), a);
                a = fmaf(wa.w, fast_rcp(fmaf(ea.w, ek[4*g+3], 1.f)), a);
                sc[qq] = a;
            }
        }
        #pragma unroll
        for (int g = 0; g < 4; ++g) e[g] = en[g];
    }

    // combine h-halves
    *(float4*)&sPart[half][kk][0] = make_float4(sc[0], sc[1], sc[2], sc[3]);
    __syncthreads();                                   // [A]
    const float4 pa = *(const float4*)&sPart[0][kk][0];
    const float4 pb = *(const float4*)&sPart[1][kk][0];
    float tot[4] = {pa.x + pb.x, pa.y + pb.y, pa.z + pb.z, pa.w + pb.w};

    // ---- softmax over k (scores = -2*tot); both halves duplicate identically ----
    const int w = tid >> 6, lane = tid & 63;
    #pragma unroll
    for (int qq = 0; qq < 4; ++qq) {
        tot[qq] = -2.0f * tot[qq];
        float mx = tot[qq];
        #pragma unroll
        for (int off = 32; off; off >>= 1) mx = fmaxf(mx, __shfl_xor(mx, off, 64));
        if (lane == 0) sredM[qq][w] = mx;
    }
    __syncthreads();                                   // [B]
    float pq[4];
    #pragma unroll
    for (int qq = 0; qq < 4; ++qq) {
        float mx = sredM[qq][0];
        #pragma unroll
        for (int i = 1; i < 8; ++i) mx = fmaxf(mx, sredM[qq][i]);
        pq[qq] = fast_exp2(LOG2E * (tot[qq] - mx));
        float s = pq[qq];
        #pragma unroll
        for (int off = 32; off; off >>= 1) s += __shfl_xor(s, off, 64);
        if (lane == 0) sredS[qq][w] = s;               // both halves contribute -> 2x true sum
    }
    if (halfu == 0) *(float4*)&sPv[kk * 4] = make_float4(pq[0], pq[1], pq[2], pq[3]);
    __syncthreads();                                   // [C]
    float rinv[4];
    #pragma unroll
    for (int qq = 0; qq < 4; ++qq) {
        float s = sredS[qq][0];
        #pragma unroll
        for (int i = 1; i < 8; ++i) s += sredS[qq][i];
        rinv[qq] = fast_rcp(0.5f * s);                 // halve the duplicated sum
    }

    // ---- PV: thread owns dv = kk, k-quads [halfu*32, halfu*32+32) ----
    float acc[4] = {0.f, 0.f, 0.f, 0.f};
    const float4* vp = (const float4*)Vp + (size_t)b * 64 * 256 + (size_t)(halfu * 32) * 256 + kk;
    float4 vv = vp[0];
    for (int k4 = 0; k4 < 32; ++k4) {
        float4 vn;
        if (k4 < 31) vn = vp[(k4 + 1) * 256];
        const int kb = (halfu * 32 + k4) * 4;
        const float vj[4] = {vv.x, vv.y, vv.z, vv.w};
        #pragma unroll
        for (int j = 0; j < 4; ++j) {
            const float4 p4 = *(const float4*)&sPv[(kb + j) * 4];   // uniform -> broadcast
            acc[0] = fmaf(p4.x, vj[j], acc[0]);
            acc[1] = fmaf(p4.y, vj[j], acc[1]);
            acc[2] = fmaf(p4.z, vj[j], acc[2]);
            acc[3] = fmaf(p4.w, vj[j], acc[3]);
        }
        vv = vn;
    }
    // combine k-halves (sPart score-reads all completed before barrier [B])
    *(float4*)&sPart[half][kk][0] = make_float4(acc[0], acc[1], acc[2], acc[3]);
    __syncthreads();                                   // [D]
    {
        const int dv = kk;
        const float4 u0 = *(const float4*)&sPart[0][dv][0];
        const float4 u1 = *(const float4*)&sPart[1][dv][0];
        float a0, a1;
        if (halfu == 0) { a0 = u0.x + u1.x; a1 = u0.y + u1.y; }
        else            { a0 = u0.z + u1.z; a1 = u0.w + u1.w; }
        float* ob = out + (size_t)(b * Qn + q0 + 2 * halfu) * DVn + dv;
        ob[0]   = a0 * rinv[2 * halfu + 0];
        ob[DVn] = a1 * rinv[2 * halfu + 1];
    }
}

extern "C" void kernel_launch(void* const* d_in, const int* in_sizes, int n_in,
                              void* d_out, int out_size, void* d_ws, size_t ws_size,
                              hipStream_t stream) {
    const float* queries = (const float*)d_in[0];  // [16,256,256]
    const float* keys    = (const float*)d_in[1];  // [16,256,256]
    const float* values  = (const float*)d_in[2];  // [16,256,256]
    const float* W_q     = (const float*)d_in[3];  // [256,256]
    const float* W_k     = (const float*)d_in[4];  // [256,256]
    const float* w_v     = (const float*)d_in[5];  // [256]
    float* out = (float*)d_out;

    // workspace: Eq fp32 4MB | Ekb bf16 2MB | Vp fp32 4MB | Xb bf16 4MB | Wb bf16 256KB
    float*          Eq  = (float*)d_ws;
    unsigned short* Ekb = (unsigned short*)(Eq + (size_t)Bn * Qn * Hn);
    float*          Vp  = (float*)(Ekb + (size_t)Bn * Kn * Hn);
    unsigned short* Xb  = (unsigned short*)(Vp + (size_t)Bn * Kn * DVn);
    unsigned short* Wb  = Xb + (size_t)2 * Bn * Qn * Hn;   // Xb holds 2*Bn*Qn*Hn bf16 elems

    prep_kernel<<<dim3(1024), 256, 0, stream>>>(queries, keys, W_q, W_k, values,
                                                Xb, Wb, Vp);
    proj_mfma_kernel<<<dim3(512), 256, 0, stream>>>(Xb, Wb, Eq, Ekb);
    fused_attn_kernel<<<dim3(64, 16), 512, 0, stream>>>(Eq, Ekb, w_v, Vp, out);
}